// Round 1
// baseline (23705.737 us; speedup 1.0000x reference)
//
#include <hip/hip_runtime.h>
#include <math.h>

// Problem: B=128, H=512, T=1024, IN=8, OUT=2. Sequential RNN over S=T-1 steps.
// Persistent kernel: 512 blocks x 256 threads = 2 blocks/CU (grid == capacity,
// so all blocks are co-resident regardless of dispatch order -> group spin is safe).
// 64 groups (2 batches each) x 8 j-blocks (64 h-rows each). W_rec slice lives in
// VGPRs (128/thread). Cross-WG h exchange via global ping-pong buffer + per-group
// per-step arrival counters with agent-scope release/acquire.

#define BB  128
#define HH  512
#define TT  1024
#define SS  1023      // T-1 scan steps
#define NIN 8
#define NG  64        // groups
#define BPG 2         // batches per group
#define NJB 8         // j-blocks per group
#define JBS 64        // h rows per j-block

__launch_bounds__(256, 2)
__global__ void rnn_persist(const float* __restrict__ inputs,   // [B][IN][T]
                            const float* __restrict__ W_in,     // [H][IN]
                            const float* __restrict__ b_in,     // [H]
                            const float* __restrict__ W_rec,    // [H][H]
                            const float* __restrict__ b_rec,    // [H]
                            const float* __restrict__ W_key,    // [2][H]
                            const float* __restrict__ b_key,    // [2]
                            float* __restrict__ out,
                            int*   __restrict__ cnt,            // [NG][1024]
                            float* __restrict__ h_buf)          // [2][NG][BPG*H]
{
    const int tid  = threadIdx.x;
    const int lane = tid & 63;
    const int wv   = tid >> 6;
    const int jb   = blockIdx.x >> 6;   // 0..7
    const int g    = blockIdx.x & 63;   // 0..63 : group's 8 blocks share blockIdx%64
    const int b0   = g * BPG;
    const int j0   = jb * JBS;

    float* keys_out = out;                         // [B][2][T]
    float* prs_out  = out + (size_t)BB * 2 * TT;   // [B][4][T]
    float* hs_out   = out + (size_t)BB * 6 * TT;   // [B][H][T]

    __shared__ float4 lds_h4[256];          // h_prev for 2 batches: [b*128 + q]
    __shared__ float  lds_part[4][2][64];   // [wave][b][j]
    __shared__ float  lds_hs[128 * 33];     // 32-step hs accumulation, stride 33 (bank-pad)
    __shared__ float  lds_win[NIN][JBS];    // W_in slice, transposed
    __shared__ float  lds_wkey[2 * HH];
    __shared__ float  lds_bias[JBS];        // b_in + b_rec
    __shared__ float  lds_x[2][NIN];
    __shared__ float  lds_key[2];           // key_{s-1}[b][0]
    __shared__ float  lds_bkey[2];
    float* lds_h = (float*)lds_h4;

    // ---- W_rec slice into registers: thread(lane,wv) holds row j0+lane, k in [wv*128, wv*128+128)
    float4 w4[32];
    {
        const float4* wr = (const float4*)(W_rec + (size_t)(j0 + lane) * HH + wv * 128);
        #pragma unroll
        for (int i = 0; i < 32; ++i) w4[i] = wr[i];
    }
    // ---- static LDS init
    for (int i = tid; i < NIN * JBS; i += 256) {
        int ii = i >> 6, j = i & 63;
        lds_win[ii][j] = W_in[(size_t)(j0 + j) * NIN + ii];
    }
    for (int i = tid; i < 2 * HH; i += 256) lds_wkey[i] = W_key[i];
    if (tid < JBS) lds_bias[tid] = b_in[j0 + tid] + b_rec[j0 + tid];
    if (tid < 2) { lds_key[tid] = 1.0f; lds_bkey[tid] = b_key[tid]; }
    for (int r = tid; r < 128; r += 256) lds_hs[r * 33] = 0.0f;   // slot u=0 (zeros column)

    // ---- zero the t=0 output slots (d_out is poisoned each call)
    for (int t = tid; t < BPG * JBS; t += 256) {
        int b = t >> 6, j = t & 63;
        hs_out[((size_t)(b0 + b) * HH + j0 + j) * TT] = 0.0f;
    }
    if (jb == 0 && tid < 4) keys_out[((size_t)(b0 + (tid >> 1)) * 2 + (tid & 1)) * TT] = 0.0f;
    if (jb == 0 && tid < 8) prs_out [((size_t)(b0 + (tid >> 2)) * 4 + (tid & 3)) * TT] = 0.0f;

    int* mycnt = cnt + g * 1024;
    const int HBUF = NG * BPG * HH;   // floats per ping-pong buffer

    __syncthreads();

    for (int s = 0; s < SS; ++s) {
        // -- wait for h_{s-1} complete (8 slices)
        if (s > 0 && tid == 0) {
            while (__hip_atomic_load(&mycnt[s - 1], __ATOMIC_RELAXED,
                                     __HIP_MEMORY_SCOPE_AGENT) != NJB)
                __builtin_amdgcn_s_sleep(1);
        }
        __syncthreads();                                   // B1
        // -- stage h_{s-1} (4 KB) into LDS
        if (s > 0) {
            __builtin_amdgcn_fence(__ATOMIC_ACQUIRE, "agent");
            const float4* hb = (const float4*)(h_buf + (size_t)((s - 1) & 1) * HBUF
                                               + (size_t)g * (BPG * HH));
            lds_h4[tid] = hb[tid];
        } else {
            lds_h4[tid] = make_float4(0.f, 0.f, 0.f, 0.f);
        }
        if (tid >= 240) {   // stage x_s (16 floats)
            int t = tid - 240, b = t >> 3, i = t & 7;
            lds_x[b][i] = inputs[(size_t)(b0 + b) * NIN * TT + (size_t)i * TT + (s + 1)];
        }
        __syncthreads();                                   // B2

        // -- recurrent partial dots: W from regs, h broadcast from LDS
        {
            const float4* h0 = &lds_h4[wv * 32];
            const float4* h1 = &lds_h4[128 + wv * 32];
            float a0 = 0.f, a1 = 0.f;
            #pragma unroll
            for (int kk = 0; kk < 32; ++kk) {
                float4 w = w4[kk], x0 = h0[kk], x1 = h1[kk];
                a0 += w.x * x0.x; a0 += w.y * x0.y; a0 += w.z * x0.z; a0 += w.w * x0.w;
                a1 += w.x * x1.x; a1 += w.y * x1.y; a1 += w.z * x1.z; a1 += w.w * x1.w;
            }
            lds_part[wv][0][lane] = a0;
            lds_part[wv][1][lane] = a1;
        }
        __syncthreads();                                   // B3

        if (tid < 128) {
            // -- finalize h_s for (b, j)
            int b = tid >> 6, j = tid & 63;
            float pre = lds_part[0][b][j] + lds_part[1][b][j]
                      + lds_part[2][b][j] + lds_part[3][b][j] + lds_bias[j];
            #pragma unroll
            for (int i = 0; i < NIN; ++i) pre += lds_x[b][i] * lds_win[i][j];
            float hv = tanhf(pre);
            h_buf[(size_t)(s & 1) * HBUF + (size_t)g * (BPG * HH) + b * HH + j0 + j] = hv;
            lds_hs[(b * 64 + j) * 33 + ((s + 1) & 31)] = hv;
        } else if (jb == 0 && s > 0) {
            // -- key_{s-1} = sigmoid(h_{s-1} @ W_key^T + b_key), waves 2-3
            int t = tid - 128;
            int b = t >> 6, c = (t >> 5) & 1, seg = t & 31;
            float p = 0.f;
            #pragma unroll
            for (int m = 0; m < 16; ++m)
                p += lds_h[b * HH + seg + 32 * m] * lds_wkey[c * HH + seg + 32 * m];
            #pragma unroll
            for (int off = 16; off > 0; off >>= 1) p += __shfl_down(p, off, 32);
            if (seg == 0) {
                float kv = 1.0f / (1.0f + __expf(-(p + lds_bkey[c])));
                keys_out[((size_t)(b0 + b) * 2 + c) * TT + s] = kv;   // slot (s-1)+1
                if (c == 0) lds_key[b] = kv;
            }
        }
        __syncthreads();                                   // B4

        // -- release h_s slice ASAP
        if (tid == 0)
            __hip_atomic_fetch_add(&mycnt[s], 1, __ATOMIC_RELEASE,
                                   __HIP_MEMORY_SCOPE_AGENT);

        // -- pr_s from x_s and key_{s-1} (off the critical path)
        if (jb == 0 && tid < 8) {
            int b = tid >> 2, c = tid & 3;
            float kv = lds_key[b];
            float tmv, arm;
            if (c < 2) { tmv = lds_x[b][6]; arm = lds_x[b][c]; }
            else       { tmv = lds_x[b][7];
                         arm = lds_x[b][c] * kv + lds_x[b][c + 2] * (1.0f - kv); }
            float r  = (tmv - arm) / (0.15f * arm);
            float pr = (tmv == 0.0f) ? 0.0f : r * r;
            prs_out[((size_t)(b0 + b) * 4 + c) * TT + (s + 1)] = pr;
        }

        // -- flush 32 accumulated hs time-slots as aligned float4 full lines
        if (((s + 1) & 31) == 31) {
            int u0 = s - 30;                 // multiple of 32
            int r = tid >> 1, half = tid & 1;
            int b = r >> 6, j = r & 63;
            float* dst = hs_out + ((size_t)(b0 + b) * HH + j0 + j) * TT + u0 + half * 16;
            const float* src = &lds_hs[r * 33 + half * 16];
            #pragma unroll
            for (int q = 0; q < 4; ++q) {
                float4 v = { src[q * 4 + 0], src[q * 4 + 1], src[q * 4 + 2], src[q * 4 + 3] };
                *(float4*)(dst + q * 4) = v;
            }
        }
    }

    // -- final key (output slot T-1) from h_{S-1}
    if (jb == 0) {
        if (tid == 0) {
            while (__hip_atomic_load(&mycnt[SS - 1], __ATOMIC_RELAXED,
                                     __HIP_MEMORY_SCOPE_AGENT) != NJB)
                __builtin_amdgcn_s_sleep(1);
        }
        __syncthreads();
        __builtin_amdgcn_fence(__ATOMIC_ACQUIRE, "agent");
        {
            const float4* hb = (const float4*)(h_buf + (size_t)((SS - 1) & 1) * HBUF
                                               + (size_t)g * (BPG * HH));
            lds_h4[tid] = hb[tid];
        }
        __syncthreads();
        if (tid >= 128) {
            int t = tid - 128;
            int b = t >> 6, c = (t >> 5) & 1, seg = t & 31;
            float p = 0.f;
            #pragma unroll
            for (int m = 0; m < 16; ++m)
                p += lds_h[b * HH + seg + 32 * m] * lds_wkey[c * HH + seg + 32 * m];
            #pragma unroll
            for (int off = 16; off > 0; off >>= 1) p += __shfl_down(p, off, 32);
            if (seg == 0) {
                float kv = 1.0f / (1.0f + __expf(-(p + lds_bkey[c])));
                keys_out[((size_t)(b0 + b) * 2 + c) * TT + (TT - 1)] = kv;
            }
        }
    }
}

extern "C" void kernel_launch(void* const* d_in, const int* in_sizes, int n_in,
                              void* d_out, int out_size, void* d_ws, size_t ws_size,
                              hipStream_t stream) {
    const float* inputs = (const float*)d_in[0];
    const float* W_in   = (const float*)d_in[1];
    const float* b_in   = (const float*)d_in[2];
    const float* W_rec  = (const float*)d_in[3];
    const float* b_rec  = (const float*)d_in[4];
    const float* W_key  = (const float*)d_in[5];
    const float* b_key  = (const float*)d_in[6];
    float* outp = (float*)d_out;

    // ws layout: cnt [NG*1024 ints] | h_buf [2*NG*BPG*H floats]  (~768 KB total)
    int*   cnt   = (int*)d_ws;
    float* h_buf = (float*)((char*)d_ws + (size_t)NG * 1024 * sizeof(int));

    // counters must start at zero every call (d_ws is re-poisoned by the harness)
    hipMemsetAsync(d_ws, 0, (size_t)NG * 1024 * sizeof(int), stream);

    rnn_persist<<<dim3(NG * NJB), dim3(256), 0, stream>>>(
        inputs, W_in, b_in, W_rec, b_rec, W_key, b_key, outp, cnt, h_buf);
}

// Round 2
// 3905.308 us; speedup vs baseline: 6.0701x; 6.0701x over previous
//
#include <hip/hip_runtime.h>
#include <math.h>

// B=128, H=512, T=1024, IN=8. Sequential RNN, S=1023 steps.
// Persistent kernel: 256 blocks x 512 threads (1 block/CU, all co-resident).
// 32 groups x 8 j-blocks; group g = blocks {jb*32+g}, handles 4 batches.
// Each block holds a 64-row x 512-col W_rec slice in VGPRs: thread(lane,wv)
// holds row lane, K in [wv*64, wv*64+64) -> 16 float4 = 64 VGPRs (no spill).
// Cross-block h exchange: RELAXED agent-scope atomics only (sc0/sc1 per-op,
// NO acquire/release fences -> no buffer_inv / buffer_wbl2 per step).
// Ordering: producer sc1-stores drained by __syncthreads' vmcnt(0) before the
// counter add; consumer loads after spin+barrier bypass stale L1/L2.

#define BB  128
#define HH  512
#define TT  1024
#define SS  1023
#define NIN 8
#define NG  32      // groups
#define BPG 4       // batches per group
#define NJB 8       // j-blocks per group
#define JBS 64      // h rows per j-block
#define NTH 512

__launch_bounds__(NTH, 2)
__global__ void rnn_persist(const float* __restrict__ inputs,   // [B][IN][T]
                            const float* __restrict__ W_in,     // [H][IN]
                            const float* __restrict__ b_in,     // [H]
                            const float* __restrict__ W_rec,    // [H][H]
                            const float* __restrict__ b_rec,    // [H]
                            const float* __restrict__ W_key,    // [2][H]
                            const float* __restrict__ b_key,    // [2]
                            float* __restrict__ out,
                            int*   __restrict__ cnt,            // [NG][1024]
                            float* __restrict__ h_buf)          // [2][NG][BPG*H]
{
    const int tid  = threadIdx.x;
    const int lane = tid & 63;
    const int wv   = tid >> 6;            // 0..7
    const int g    = blockIdx.x & (NG - 1);
    const int jb   = blockIdx.x >> 5;     // 0..7
    const int b0   = g * BPG;
    const int j0   = jb * JBS;

    float* keys_out = out;                         // [B][2][T]
    float* prs_out  = out + (size_t)BB * 2 * TT;   // [B][4][T]
    float* hs_out   = out + (size_t)BB * 6 * TT;   // [B][H][T]

    __shared__ float lds_h[BPG * HH];          // h_{s-1}, 4 batches (8 KB)
    __shared__ float lds_part[8][BPG][JBS];    // [wave][b][j] partials (8 KB)
    __shared__ float lds_hs[BPG * JBS * 33];   // 32-step hs accum, stride 33
    __shared__ float lds_win[NIN][JBS];        // W_in slice (transposed)
    __shared__ float lds_wkey[2 * HH];
    __shared__ float lds_bias[JBS];            // b_in + b_rec
    __shared__ float lds_x2[2][BPG][NIN];      // x double buffer
    __shared__ float lds_key[BPG];             // key_{s-1}[b][0]
    __shared__ float lds_bkey[2];

    // ---- W_rec slice -> registers (16 float4 = 64 VGPRs)
    float4 w4[16];
    {
        const float4* wr = (const float4*)(W_rec + (size_t)(j0 + lane) * HH + wv * 64);
        #pragma unroll
        for (int i = 0; i < 16; ++i) w4[i] = wr[i];
    }
    // ---- static LDS init
    if (tid < NIN * JBS) {
        int i = tid >> 6, j = tid & 63;
        lds_win[i][j] = W_in[(size_t)(j0 + j) * NIN + i];
    }
    for (int i = tid; i < 2 * HH; i += NTH) lds_wkey[i] = W_key[i];
    if (tid < JBS) lds_bias[tid] = b_in[j0 + tid] + b_rec[j0 + tid];
    if (tid < BPG) lds_key[tid] = 1.0f;
    if (tid < 2)   lds_bkey[tid] = b_key[tid];
    for (int r = tid; r < BPG * JBS; r += NTH) lds_hs[r * 33] = 0.0f;  // zero col

    // ---- zero t=0 slots for keys/prs (hs slot 0 comes from the zero column)
    if (jb == 0) {
        if (tid < BPG * 2) keys_out[((size_t)(b0 + (tid >> 1)) * 2 + (tid & 1)) * TT] = 0.0f;
        if (tid < BPG * 4) prs_out [((size_t)(b0 + (tid >> 2)) * 4 + (tid & 3)) * TT] = 0.0f;
    }

    int* mycnt = cnt + g * 1024;
    const int HBUF = NG * BPG * HH;   // floats per ping-pong half

    __syncthreads();

    for (int s = 0; s < SS; ++s) {
        // -- stage x_s (independent of h; double-buffered on s&1)
        if (tid >= NTH - 32) {
            int t = tid - (NTH - 32), b = t >> 3, i = t & 7;
            lds_x2[s & 1][b][i] = inputs[(size_t)(b0 + b) * NIN * TT + (size_t)i * TT + (s + 1)];
        }
        // -- wait for h_{s-1} (8 slices)
        if (s > 0 && tid == 0) {
            while (__hip_atomic_load(&mycnt[s - 1], __ATOMIC_RELAXED,
                                     __HIP_MEMORY_SCOPE_AGENT) != NJB) {}
        }
        __syncthreads();                                   // B1
        // -- load h_{s-1} into LDS (coherence-point loads, no cache-maint ops)
        if (s > 0) {
            const float* hb = h_buf + (size_t)((s - 1) & 1) * HBUF + (size_t)g * (BPG * HH);
            #pragma unroll
            for (int q = 0; q < 4; ++q)
                lds_h[tid + NTH * q] = __hip_atomic_load(&hb[tid + NTH * q],
                                                         __ATOMIC_RELAXED,
                                                         __HIP_MEMORY_SCOPE_AGENT);
        } else {
            #pragma unroll
            for (int q = 0; q < 4; ++q) lds_h[tid + NTH * q] = 0.0f;
        }
        __syncthreads();                                   // B2

        // -- partial dots: W from regs, h broadcast from LDS
        {
            const float4* hp = (const float4*)lds_h + wv * 16;
            float a0 = 0.f, a1 = 0.f, a2 = 0.f, a3 = 0.f;
            #pragma unroll
            for (int kk = 0; kk < 16; ++kk) {
                float4 w  = w4[kk];
                float4 x0 = hp[kk], x1 = hp[128 + kk], x2 = hp[256 + kk], x3 = hp[384 + kk];
                a0 += w.x * x0.x + w.y * x0.y + w.z * x0.z + w.w * x0.w;
                a1 += w.x * x1.x + w.y * x1.y + w.z * x1.z + w.w * x1.w;
                a2 += w.x * x2.x + w.y * x2.y + w.z * x2.z + w.w * x2.w;
                a3 += w.x * x3.x + w.y * x3.y + w.z * x3.z + w.w * x3.w;
            }
            lds_part[wv][0][lane] = a0;
            lds_part[wv][1][lane] = a1;
            lds_part[wv][2][lane] = a2;
            lds_part[wv][3][lane] = a3;
        }
        __syncthreads();                                   // B3

        if (tid < BPG * JBS) {
            // -- finalize h_s for (b, j); store to exchange buffer
            int b = tid >> 6, j = tid & 63;
            float pre = lds_bias[j];
            #pragma unroll
            for (int w = 0; w < 8; ++w) pre += lds_part[w][b][j];
            #pragma unroll
            for (int i = 0; i < NIN; ++i) pre += lds_x2[s & 1][b][i] * lds_win[i][j];
            float hv = tanhf(pre);
            __hip_atomic_store(&h_buf[(size_t)(s & 1) * HBUF + (size_t)g * (BPG * HH)
                                      + b * HH + j0 + j],
                               hv, __ATOMIC_RELAXED, __HIP_MEMORY_SCOPE_AGENT);
            lds_hs[(b * JBS + j) * 33 + ((s + 1) & 31)] = hv;
        } else if (jb == 0 && s > 0) {
            // -- key_{s-1} = sigmoid(h_{s-1} @ W_key^T + b_key): 8 dots x 32 thr
            int t2  = tid - 256;
            int dot = t2 >> 5;          // 0..7
            int b = dot >> 1, c = dot & 1, seg = t2 & 31;
            float p = 0.f;
            #pragma unroll
            for (int m = 0; m < 16; ++m)
                p += lds_h[b * HH + seg + 32 * m] * lds_wkey[c * HH + seg + 32 * m];
            #pragma unroll
            for (int off = 16; off > 0; off >>= 1) p += __shfl_down(p, off, 32);
            if (seg == 0) {
                float kv = 1.0f / (1.0f + __expf(-(p + lds_bkey[c])));
                keys_out[((size_t)(b0 + b) * 2 + c) * TT + s] = kv;
                if (c == 0) lds_key[b] = kv;
            }
        }
        __syncthreads();   // B4: drains sc1 h-stores (vmcnt 0) before release

        // -- release this block's slice of h_s
        if (tid == 0)
            __hip_atomic_fetch_add(&mycnt[s], 1, __ATOMIC_RELAXED,
                                   __HIP_MEMORY_SCOPE_AGENT);

        // -- prs (off critical path)
        if (jb == 0 && tid < BPG * 4) {
            int b = tid >> 2, c = tid & 3;
            float kv = lds_key[b];
            const float* xb = lds_x2[s & 1][b];
            float tmv, arm;
            if (c < 2) { tmv = xb[6]; arm = xb[c]; }
            else       { tmv = xb[7]; arm = xb[c] * kv + xb[c + 2] * (1.0f - kv); }
            float r = (tmv - arm) / (0.15f * arm);
            prs_out[((size_t)(b0 + b) * 4 + c) * TT + (s + 1)] = (tmv == 0.0f) ? 0.0f : r * r;
        }

        // -- flush 32 accumulated hs time-slots (128 B contiguous per row)
        if (((s + 1) & 31) == 31) {
            int u0 = s - 30;                  // multiple of 32
            int r = tid >> 1, half = tid & 1;
            int b = r >> 6, j = r & 63;
            float* dst = hs_out + ((size_t)(b0 + b) * HH + j0 + j) * TT + u0 + half * 16;
            const float* src = &lds_hs[r * 33 + half * 16];
            #pragma unroll
            for (int q = 0; q < 4; ++q) {
                float4 v = { src[4 * q], src[4 * q + 1], src[4 * q + 2], src[4 * q + 3] };
                *(float4*)(dst + 4 * q) = v;
            }
        }
    }

    // -- final key (slot T-1) from h_{S-1}
    if (jb == 0) {
        if (tid == 0) {
            while (__hip_atomic_load(&mycnt[SS - 1], __ATOMIC_RELAXED,
                                     __HIP_MEMORY_SCOPE_AGENT) != NJB) {}
        }
        __syncthreads();
        {
            const float* hb = h_buf + (size_t)((SS - 1) & 1) * HBUF + (size_t)g * (BPG * HH);
            #pragma unroll
            for (int q = 0; q < 4; ++q)
                lds_h[tid + NTH * q] = __hip_atomic_load(&hb[tid + NTH * q],
                                                         __ATOMIC_RELAXED,
                                                         __HIP_MEMORY_SCOPE_AGENT);
        }
        __syncthreads();
        if (tid >= 256) {
            int t2  = tid - 256;
            int dot = t2 >> 5;
            int b = dot >> 1, c = dot & 1, seg = t2 & 31;
            float p = 0.f;
            #pragma unroll
            for (int m = 0; m < 16; ++m)
                p += lds_h[b * HH + seg + 32 * m] * lds_wkey[c * HH + seg + 32 * m];
            #pragma unroll
            for (int off = 16; off > 0; off >>= 1) p += __shfl_down(p, off, 32);
            if (seg == 0) {
                float kv = 1.0f / (1.0f + __expf(-(p + lds_bkey[c])));
                keys_out[((size_t)(b0 + b) * 2 + c) * TT + (TT - 1)] = kv;
            }
        }
    }
}

extern "C" void kernel_launch(void* const* d_in, const int* in_sizes, int n_in,
                              void* d_out, int out_size, void* d_ws, size_t ws_size,
                              hipStream_t stream) {
    const float* inputs = (const float*)d_in[0];
    const float* W_in   = (const float*)d_in[1];
    const float* b_in   = (const float*)d_in[2];
    const float* W_rec  = (const float*)d_in[3];
    const float* b_rec  = (const float*)d_in[4];
    const float* W_key  = (const float*)d_in[5];
    const float* b_key  = (const float*)d_in[6];
    float* outp = (float*)d_out;

    // ws layout: cnt [NG*1024 ints] | h_buf [2*NG*BPG*H floats]  (~640 KB)
    int*   cnt   = (int*)d_ws;
    float* h_buf = (float*)((char*)d_ws + (size_t)NG * 1024 * sizeof(int));

    hipMemsetAsync(d_ws, 0, (size_t)NG * 1024 * sizeof(int), stream);

    rnn_persist<<<dim3(NG * NJB), dim3(NTH), 0, stream>>>(
        inputs, W_in, b_in, W_rec, b_rec, W_key, b_key, outp, cnt, h_buf);
}